// Round 8
// baseline (95.762 us; speedup 1.0000x reference)
//
#include <hip/hip_runtime.h>
#include <hip/hip_fp16.h>

// Problem constants
#define N_VISITS  16384
#define MAX_CODES 64
#define DIM       64
#define NUM_CODES 100000

typedef float f32x4 __attribute__((ext_vector_type(4)));

// ---------------------------------------------------------------------------
// Kernel A: convert emb table fp32 -> fp16 (12.8 MB). Exact grid: 3125 x 256
// threads = 800000 16B->8B conversions, one per thread, no loop. ~6.5 us.
// nt loads (fp32 read once) and nt stores (don't linger dirty in per-XCD
// L2s; the warm kernel will install the table clean in L3).
// ---------------------------------------------------------------------------
__global__ __launch_bounds__(256) void emb_to_half_kernel(
    const float* __restrict__ emb, __half* __restrict__ embh)
{
    const size_t i = (size_t)blockIdx.x * 256 + threadIdx.x;   // 0..799999
    const f32x4* src = (const f32x4*)emb + 2 * i;
    f32x4 a = __builtin_nontemporal_load(src);
    f32x4 b = __builtin_nontemporal_load(src + 1);
    union { __half2 h[4]; f32x4 f; } u;
    u.h[0] = __floats2half2_rn(a.x, a.y);
    u.h[1] = __floats2half2_rn(a.z, a.w);
    u.h[2] = __floats2half2_rn(b.x, b.y);
    u.h[3] = __floats2half2_rn(b.z, b.w);
    __builtin_nontemporal_store(u.f, (f32x4*)embh + i);
}

// ---------------------------------------------------------------------------
// Kernel W: table warm pass. One streaming, coalesced read of the whole
// 12.8 MB fp16 table (one f32x4 per thread, exact grid). Every line is
// installed CLEAN in the memory-side Infinity Cache (L3) — and partially in
// the readers' L2s — so the following random gather runs the warm path
// (~16 us measured in R5) instead of the cold first-touch path (~41 us,
// R2/R7). The asm sink keeps the loads live (no DCE) at zero cost.
// Correctness does not depend on this kernel.
// ---------------------------------------------------------------------------
__global__ __launch_bounds__(256) void table_warm_kernel(
    const __half* __restrict__ embh)
{
    const size_t i = (size_t)blockIdx.x * 256 + threadIdx.x;   // 0..799999
    f32x4 v = ((const f32x4*)embh)[i];
    asm volatile("" :: "v"(v.x), "v"(v.y), "v"(v.z), "v"(v.w));
}

// ---------------------------------------------------------------------------
// Kernel B: monolithic gather + masked mean (byte-identical to the kernel
// measured at ~16 us warm in R5). One wave per visit. r = lane>>3 (8 row
// slots), t = lane&7 (16B chunk of the 128B fp16 row). All 8 gathers (1 KB
// per wave instruction) issued before any accumulation.
// ---------------------------------------------------------------------------
__global__ __launch_bounds__(256) void visit_mean_kernel(
    const int* __restrict__ code_ids,
    const __half* __restrict__ embh,
    float* __restrict__ out)
{
    const int wave_in_block = threadIdx.x >> 6;
    const int lane = threadIdx.x & 63;
    const int visit = blockIdx.x * 4 + wave_in_block;

    const int r = lane >> 3;
    const int t = lane & 7;

    const int my_id = __builtin_nontemporal_load(
        code_ids + (size_t)visit * MAX_CODES + lane);
    const unsigned long long valid = __ballot(my_id >= 0);
    const int count = __popcll(valid);

    int ids[8];
    #pragma unroll
    for (int j = 0; j < 8; ++j) ids[j] = __shfl(my_id, 8 * j + r, 64);

    f32x4 v[8];
    #pragma unroll
    for (int j = 0; j < 8; ++j) {
        const int id   = ids[j];
        const int safe = (id >= 0) ? id : 0;
        v[j] = *((const f32x4*)(embh + (size_t)safe * DIM) + t);
    }

    float acc[8] = {0.f,0.f,0.f,0.f,0.f,0.f,0.f,0.f};
    #pragma unroll
    for (int j = 0; j < 8; ++j) {
        const float m = (ids[j] >= 0) ? 1.0f : 0.0f;
        const __half2* h = (const __half2*)&v[j];
        #pragma unroll
        for (int k = 0; k < 4; ++k) {
            const float2 f = __half22float2(h[k]);
            acc[2 * k]     = fmaf(m, f.x, acc[2 * k]);
            acc[2 * k + 1] = fmaf(m, f.y, acc[2 * k + 1]);
        }
    }

    #pragma unroll
    for (int k = 0; k < 8; ++k) acc[k] += __shfl_xor(acc[k], 8, 64);
    #pragma unroll
    for (int k = 0; k < 8; ++k) acc[k] += __shfl_xor(acc[k], 16, 64);
    #pragma unroll
    for (int k = 0; k < 8; ++k) acc[k] += __shfl_xor(acc[k], 32, 64);

    if (lane < 8) {
        const float scale = (count > 0) ? (1.0f / (float)count) : 0.0f;
        f32x4 o0, o1;
        o0.x = acc[0] * scale; o0.y = acc[1] * scale;
        o0.z = acc[2] * scale; o0.w = acc[3] * scale;
        o1.x = acc[4] * scale; o1.y = acc[5] * scale;
        o1.z = acc[6] * scale; o1.w = acc[7] * scale;
        f32x4* dst = (f32x4*)(out + (size_t)visit * DIM + lane * 8);
        __builtin_nontemporal_store(o0, dst);
        __builtin_nontemporal_store(o1, dst + 1);
    }
}

extern "C" void kernel_launch(void* const* d_in, const int* in_sizes, int n_in,
                              void* d_out, int out_size, void* d_ws, size_t ws_size,
                              hipStream_t stream) {
    const int*   code_ids = (const int*)d_in[0];    // [N_VISITS, MAX_CODES] int32
    const float* emb      = (const float*)d_in[1];  // [NUM_CODES, DIM] fp32
    float*       out      = (float*)d_out;          // [N_VISITS, DIM] fp32
    __half*      embh     = (__half*)d_ws;          // 12.8 MB fp16 table

    // A: fp32 -> fp16 table (nt loads + nt stores)
    emb_to_half_kernel<<<3125, 256, 0, stream>>>(emb, embh);

    // W: streaming read pass installs the table clean in L3 (+ L2s)
    table_warm_kernel<<<3125, 256, 0, stream>>>(embh);

    // B: monolithic gather + masked mean, one wave per visit
    visit_mean_kernel<<<4096, 256, 0, stream>>>(code_ids, embh, out);
}